// Round 10
// baseline (267.953 us; speedup 1.0000x reference)
//
#include <hip/hip_runtime.h>
#include <hip/hip_bf16.h>

// Problem constants: B=2, T=2048, C=1024, H=16, D=64
#define MHSA_B 2
#define MHSA_T 2048
#define MHSA_C 1024
#define MHSA_H 16
#define MHSA_D 64

typedef __attribute__((ext_vector_type(8))) short bf16x8_t;          // 8 bf16
typedef __attribute__((ext_vector_type(4))) float f32x4_t;           // 4 fp32

// fp32 -> bf16 round-to-nearest-even
__device__ __forceinline__ unsigned short f2bf(float f) {
    unsigned int u = __float_as_uint(f);
    u = u + 0x7FFFu + ((u >> 16) & 1u);
    return (unsigned short)(u >> 16);
}

// async global->LDS, 16 B per lane (staging; LDS dest = uniform base + lane*16)
__device__ __forceinline__ void gload_lds16(const void* g, void* l) {
    __builtin_amdgcn_global_load_lds(
        (const __attribute__((address_space(1))) void*)g,
        (__attribute__((address_space(3))) void*)l, 16, 0, 0);
}

__device__ __forceinline__ float rowred_max(float t) {
    t = fmaxf(t, __shfl_xor(t, 1));
    t = fmaxf(t, __shfl_xor(t, 2));
    t = fmaxf(t, __shfl_xor(t, 4));
    t = fmaxf(t, __shfl_xor(t, 8));
    return t;
}
__device__ __forceinline__ float rowred_sum(float t) {
    t += __shfl_xor(t, 1);
    t += __shfl_xor(t, 2);
    t += __shfl_xor(t, 4);
    t += __shfl_xor(t, 8);
    return t;
}

// ---------------------------------------------------------------------------
// fp32 -> bf16 convert (vectorized)
// ---------------------------------------------------------------------------
__global__ __launch_bounds__(256)
void f32_to_bf16_kernel(const float* __restrict__ in,
                        unsigned short* __restrict__ out, int n4) {
    int i = blockIdx.x * blockDim.x + threadIdx.x;
    const int stride = gridDim.x * blockDim.x;
    for (; i < n4; i += stride) {
        float4 v = *(const float4*)&in[(size_t)i * 4];
        ushort4 u;
        u.x = f2bf(v.x); u.y = f2bf(v.y); u.z = f2bf(v.z); u.w = f2bf(v.w);
        *(ushort4*)&out[(size_t)i * 4] = u;
    }
}

// ---------------------------------------------------------------------------
// Transpose + convert: W fp32 [R][Ncols] -> WT bf16 [Ncols][R]
// ---------------------------------------------------------------------------
__global__ __launch_bounds__(256)
void transpose_to_bf16_kernel(const float* __restrict__ W,
                              unsigned short* __restrict__ WT,
                              int R, int Ncols) {
    __shared__ float tile[32][33];
    const int c0 = blockIdx.x * 32;
    const int r0 = blockIdx.y * 32;
    const int tx = threadIdx.x & 31;
    const int ty = threadIdx.x >> 5;
#pragma unroll
    for (int i = 0; i < 32; i += 8)
        tile[ty + i][tx] = W[(size_t)(r0 + ty + i) * Ncols + c0 + tx];
    __syncthreads();
#pragma unroll
    for (int i = 0; i < 32; i += 8)
        WT[(size_t)(c0 + ty + i) * R + r0 + tx] = f2bf(tile[tx][ty + i]);
}

// ---------------------------------------------------------------------------
// bf16 MFMA GEMM (m97 structure): C[M,N] = A[M,K] @ Bt[N,K]^T + bias
// MODE 0: fp32 out row-major.
// MODE 2 (QKV): bf16 out row-major for cols < 2C; V third (cols >= 2C)
//         written TRANSPOSED to vtb[(b*16+h)*64+d][T] (packed ushort4).
// ---------------------------------------------------------------------------
template <int MODE>
__global__ __launch_bounds__(256)
void gemm_bf16_mfma(const unsigned short* __restrict__ A,
                    const unsigned short* __restrict__ Bt,
                    const float* __restrict__ bias,
                    void* __restrict__ Cout,
                    unsigned short* __restrict__ vtb,
                    int M, int N, int K) {
    __shared__ unsigned short As[128 * 32];
    __shared__ unsigned short Bs[128 * 32];

    const int tid  = threadIdx.x;
    const int lane = tid & 63;
    const int w    = tid >> 6;
    const int bm   = blockIdx.y * 128;
    const int bn   = blockIdx.x * 128;
    const int wr   = (w >> 1) * 64;
    const int wc   = (w & 1) * 64;

    f32x4_t acc[4][4];
#pragma unroll
    for (int m = 0; m < 4; ++m)
#pragma unroll
        for (int n = 0; n < 4; ++n) acc[m][n] = (f32x4_t){0.f, 0.f, 0.f, 0.f};

    const int rS = lane >> 2;
    const int kS = (lane & 3) * 8;

    for (int k0 = 0; k0 < K; k0 += 32) {
        __syncthreads();
#pragma unroll
        for (int c = 0; c < 2; ++c) {
            const int row = c * 64 + w * 16 + rS;
            gload_lds16(&A[(size_t)(bm + row) * K + k0 + kS],
                        &As[c * 2048 + w * 512]);
            gload_lds16(&Bt[(size_t)(bn + row) * K + k0 + kS],
                        &Bs[c * 2048 + w * 512]);
        }
        __syncthreads();

        bf16x8_t a[4], b[4];
#pragma unroll
        for (int m = 0; m < 4; ++m)
            a[m] = *(const bf16x8_t*)&As[(wr + m * 16 + (lane & 15)) * 32 + (lane >> 4) * 8];
#pragma unroll
        for (int n = 0; n < 4; ++n)
            b[n] = *(const bf16x8_t*)&Bs[(wc + n * 16 + (lane & 15)) * 32 + (lane >> 4) * 8];
#pragma unroll
        for (int m = 0; m < 4; ++m)
#pragma unroll
            for (int n = 0; n < 4; ++n)
                acc[m][n] = __builtin_amdgcn_mfma_f32_16x16x32_bf16(a[m], b[n], acc[m][n], 0, 0, 0);
    }

    // epilogue: C/D layout col=lane&15, row=(lane>>4)*4+reg [m89/m91]
    const int cq = lane >> 4;
    const int cr = lane & 15;
#pragma unroll
    for (int n = 0; n < 4; ++n) {
        const int col = bn + wc + n * 16 + cr;
        const float bv = bias[col];
        const int rowb = bm + wr + cq * 4;    // +m*16 +r
#pragma unroll
        for (int m = 0; m < 4; ++m) {
            if (MODE == 2 && col >= 2 * MHSA_C) {
                // V third: write transposed vtb[(b*16+h)*64+d][t], packed x4
                const int vcol = col - 2 * MHSA_C;
                const int h = vcol >> 6;
                const int d = vcol & 63;
                const int tg = rowb + m * 16;         // global token row
                const int bb = tg >> 11;              // /T
                const int tt = tg & (MHSA_T - 1);
                ushort4 u;
                u.x = f2bf(acc[m][n][0] + bv);
                u.y = f2bf(acc[m][n][1] + bv);
                u.z = f2bf(acc[m][n][2] + bv);
                u.w = f2bf(acc[m][n][3] + bv);
                *(ushort4*)&vtb[(size_t)((bb * 16 + h) * 64 + d) * MHSA_T + tt] = u;
            } else {
#pragma unroll
                for (int r = 0; r < 4; ++r) {
                    const int row = rowb + m * 16 + r;
                    const float val = acc[m][n][r] + bv;
                    if (MODE == 0)
                        ((float*)Cout)[(size_t)row * N + col] = val;
                    else
                        ((unsigned short*)Cout)[(size_t)row * N + col] = f2bf(val);
                }
            }
        }
    }
}

// ---------------------------------------------------------------------------
// MFMA flash attention (causal), K/V staged in LDS via global_load_lds with
// T21 both-sides XOR swizzle (linear LDS dest; source pre-swizzled; reads
// XOR chunk with row&7) -> coalesced staging (8 x 128B rows per instr) AND
// conflict-free ds_read_b128 (2-way max, free per m136).
// One 64-thread wave per (b, h, 32-row q-tile); grid 2048.
// LDS: Ks 8KB + Vs 8KB + Ps 4.6KB = 20.6KB -> ~7 blocks/CU.
// Softmax on verified C-layout: col=lane&15, row=(lane>>4)*4+reg.
// ---------------------------------------------------------------------------
__global__ __launch_bounds__(64, 2)
void attn_mfma_kernel(const unsigned short* __restrict__ qkvb,
                      const unsigned short* __restrict__ vtb,
                      unsigned short* __restrict__ attb) {
    constexpr int T = MHSA_T, C = MHSA_C;
    constexpr int C3 = 3 * C;
    constexpr int LS = 72;                    // Ps row stride (144 B)

    __shared__ unsigned short Ks[64 * 64];    // K[kcol][d], rows 128B, swizzled chunks
    __shared__ unsigned short Vs[64 * 64];    // V^T[d][kcol], rows 128B, swizzled chunks
    __shared__ unsigned short Ps[32 * LS];    // P[q][kcol]

    const int l = threadIdx.x;
    const int c = l & 15;
    const int g = l >> 4;
    const int idx = blockIdx.x;
    const int bh = idx & 31;
    const int h = bh & 15;
    const int b = bh >> 4;
    const int qt = 63 - (idx >> 5);           // longest first
    const int q0 = qt * 32;
    const size_t rowbase = (size_t)(b * T) * C3;

    // staging decomposition: lane covers row sr of each 8-row group, chunk sc.
    // Value stored at physical chunk sc must be logical chunk sc^(row&7)=sc^sr.
    const int sr = l >> 3;                    // 0..7
    const int sc = l & 7;                     // 0..7 (16B chunks)
    const int schunk = (sc ^ sr) * 8;         // source elem offset (8 ushorts=16B)

    // Q fragments: row = m*16 + c, d = ks*32 + g*8 + j  (direct global, once)
    bf16x8_t qf[2][2];
    const unsigned short* Qg = qkvb + rowbase + (size_t)q0 * C3 + h * 64;
#pragma unroll
    for (int m = 0; m < 2; ++m)
#pragma unroll
        for (int ks = 0; ks < 2; ++ks)
            qf[m][ks] = *(const bf16x8_t*)(Qg + (size_t)(m * 16 + c) * C3 + ks * 32 + g * 8);

    f32x4_t acc_o[2][4];
#pragma unroll
    for (int m = 0; m < 2; ++m)
#pragma unroll
        for (int dn = 0; dn < 4; ++dn) acc_o[m][dn] = (f32x4_t){0.f, 0.f, 0.f, 0.f};
    float mrun[2][4], lrun[2][4];
#pragma unroll
    for (int m = 0; m < 2; ++m)
#pragma unroll
        for (int j = 0; j < 4; ++j) { mrun[m][j] = -1e30f; lrun[m][j] = 0.f; }

    const unsigned short* Kg = qkvb + rowbase + C + h * 64;
    const unsigned short* Vg = vtb + (size_t)(bh * 64) * T;

    for (int k0 = 0; k0 <= q0 + 31; k0 += 64) {
        __syncthreads();   // previous tile's LDS readers done
        // ---- stage K tile [64 kcol][64 d] and V^T tile [64 d][64 kcol] ----
        // per instr: 64 lanes x 16B = 8 rows x 128B, coalesced; source chunk
        // pre-swizzled so linear LDS holds chunk' = chunk ^ (row&7).
#pragma unroll
        for (int i = 0; i < 8; ++i) {
            const int r = i * 8 + sr;
            gload_lds16(Kg + (size_t)(k0 + r) * C3 + schunk, &Ks[i * 512]);
            gload_lds16(Vg + (size_t)r * T + k0 + schunk, &Vs[i * 512]);
        }
        __syncthreads();   // drains vmcnt(0): staged data visible

        // ---- S = Q @ K^T (K frags from LDS, swizzled read) ----
        f32x4_t sA[2][4];
#pragma unroll
        for (int m = 0; m < 2; ++m)
#pragma unroll
            for (int n = 0; n < 4; ++n) sA[m][n] = (f32x4_t){0.f, 0.f, 0.f, 0.f};
#pragma unroll
        for (int ks = 0; ks < 2; ++ks) {
            bf16x8_t kf[4];
#pragma unroll
            for (int n = 0; n < 4; ++n) {
                const int row = n * 16 + c;
                kf[n] = *(const bf16x8_t*)&Ks[row * 64 + (((ks * 4 + g) ^ (row & 7)) * 8)];
            }
#pragma unroll
            for (int m = 0; m < 2; ++m)
#pragma unroll
                for (int n = 0; n < 4; ++n)
                    sA[m][n] = __builtin_amdgcn_mfma_f32_16x16x32_bf16(qf[m][ks], kf[n], sA[m][n], 0, 0, 0);
        }

        // ---- scale + causal mask (diagonal-overlap tiles only) ----
        const bool diag = (k0 + 64 > q0);
#pragma unroll
        for (int m = 0; m < 2; ++m)
#pragma unroll
            for (int n = 0; n < 4; ++n)
#pragma unroll
                for (int j = 0; j < 4; ++j) {
                    float sv = sA[m][n][j] * 0.125f;   // 1/sqrt(64)
                    if (diag) {
                        const int col = k0 + n * 16 + c;
                        const int row = q0 + m * 16 + g * 4 + j;
                        sv = (col <= row) ? sv : -1e30f;
                    }
                    sA[m][n][j] = sv;
                }

        // ---- online softmax: rows live in 16-lane groups ----
#pragma unroll
        for (int m = 0; m < 2; ++m)
#pragma unroll
            for (int j = 0; j < 4; ++j) {
                float t = fmaxf(fmaxf(sA[m][0][j], sA[m][1][j]),
                                fmaxf(sA[m][2][j], sA[m][3][j]));
                t = rowred_max(t);
                const float mn = fmaxf(mrun[m][j], t);
                const float scl = __expf(mrun[m][j] - mn);
                mrun[m][j] = mn;
#pragma unroll
                for (int dn = 0; dn < 4; ++dn) acc_o[m][dn][j] *= scl;
                float ps = 0.f;
#pragma unroll
                for (int n = 0; n < 4; ++n) {
                    const float p = __expf(sA[m][n][j] - mn);
                    Ps[(m * 16 + g * 4 + j) * LS + n * 16 + c] = f2bf(p);
                    ps += p;
                }
                ps = rowred_sum(ps);
                lrun[m][j] = lrun[m][j] * scl + ps;
            }
        __syncthreads();   // Ps visible (single wave: cheap lgkm drain)

        // ---- O += P @ V (P from Ps, V frags from LDS swizzled read) ----
#pragma unroll
        for (int ks = 0; ks < 2; ++ks) {
            bf16x8_t pf[2], vf[4];
#pragma unroll
            for (int m = 0; m < 2; ++m)
                pf[m] = *(const bf16x8_t*)&Ps[(m * 16 + c) * LS + ks * 32 + g * 8];
#pragma unroll
            for (int dn = 0; dn < 4; ++dn) {
                const int row = dn * 16 + c;
                vf[dn] = *(const bf16x8_t*)&Vs[row * 64 + (((ks * 4 + g) ^ (row & 7)) * 8)];
            }
#pragma unroll
            for (int m = 0; m < 2; ++m)
#pragma unroll
                for (int dn = 0; dn < 4; ++dn)
                    acc_o[m][dn] = __builtin_amdgcn_mfma_f32_16x16x32_bf16(pf[m], vf[dn], acc_o[m][dn], 0, 0, 0);
        }
    }

    // ---- epilogue: O / l -> attb bf16 ----
    unsigned short* Og = attb + (size_t)(b * T + q0) * C + h * 64;
#pragma unroll
    for (int m = 0; m < 2; ++m)
#pragma unroll
        for (int j = 0; j < 4; ++j) {
            const float inv = 1.f / lrun[m][j];
#pragma unroll
            for (int dn = 0; dn < 4; ++dn)
                Og[(size_t)(m * 16 + g * 4 + j) * C + dn * 16 + c] =
                    f2bf(acc_o[m][dn][j] * inv);
        }
}

// ---------------------------------------------------------------------------
// Launch. ws layout (all bf16 = ushort):
//   qkvb [4096][3072] 24 MiB (V third unwritten/unused)
//   vtb  [2048][2048]  8 MiB (V transposed per (b,h): [64 d][2048 t])
//   xb   [4096][1024]  8 MiB | attb [4096][1024] 8 MiB
//   wqkvT [3072][1024] 6 MiB | woutT [1024][1024] 2 MiB   (56 MiB total)
// ---------------------------------------------------------------------------
extern "C" void kernel_launch(void* const* d_in, const int* in_sizes, int n_in,
                              void* d_out, int out_size, void* d_ws, size_t ws_size,
                              hipStream_t stream) {
    const float* x     = (const float*)d_in[0];
    const float* w_qkv = (const float*)d_in[1];
    const float* b_qkv = (const float*)d_in[2];
    const float* w_out = (const float*)d_in[3];
    const float* b_out = (const float*)d_in[4];
    float* out = (float*)d_out;

    constexpr int BT = MHSA_B * MHSA_T;  // 4096
    constexpr int C  = MHSA_C;           // 1024
    constexpr int C3 = 3 * C;            // 3072

    unsigned short* qkvb  = (unsigned short*)d_ws;
    unsigned short* vtb   = qkvb + (size_t)BT * C3;
    unsigned short* xb    = vtb + (size_t)2048 * 2048;
    unsigned short* attb  = xb + (size_t)BT * C;
    unsigned short* wqkvT = attb + (size_t)BT * C;
    unsigned short* woutT = wqkvT + (size_t)C3 * C;

    f32_to_bf16_kernel<<<2048, 256, 0, stream>>>(x, xb, BT * C / 4);
    transpose_to_bf16_kernel<<<dim3(C3 / 32, C / 32), 256, 0, stream>>>(
        w_qkv, wqkvT, C, C3);
    transpose_to_bf16_kernel<<<dim3(C / 32, C / 32), 256, 0, stream>>>(
        w_out, woutT, C, C);

    // 1) qkv = x @ w_qkv + b_qkv -> bf16 (Q,K row-major; V transposed to vtb)
    gemm_bf16_mfma<2><<<dim3(C3 / 128, BT / 128), 256, 0, stream>>>(
        xb, wqkvT, b_qkv, qkvb, vtb, BT, C3, C);

    // 2) causal MFMA flash attention -> attb bf16
    attn_mfma_kernel<<<dim3(2048), dim3(64), 0, stream>>>(qkvb, vtb, attb);

    // 3) out = att @ w_out + b_out -> fp32
    gemm_bf16_mfma<0><<<dim3(C / 128, BT / 128), 256, 0, stream>>>(
        attb, woutT, b_out, out, nullptr, BT, C, C);
}